// Round 19
// baseline (347.768 us; speedup 1.0000x reference)
//
#include <hip/hip_runtime.h>
#include <hip/hip_fp16.h>

// GDE func: out = MLP(relu(mean_agg(z,edges)@Wg + z@Ws + bg))
// Round 18 -> 19: traffic/locality trims.
//  (1) Xc deleted: fused12 phase-1 stages A directly from Xm (gather mean,
//      k0<128) and z16 (k0>=128) -- saves 25.6MB write + dedup read.
//  (2) gemm3 1D grid + XCD-chunked swizzle so the (x,0),(x,1) pair sharing
//      an A-panel (128KB of h2) lands on the same XCD -> L2-hot 2nd read.
// All kernels otherwise frozen at measured best.

typedef _Float16 f16;
typedef __attribute__((ext_vector_type(4))) _Float16 f16x4;
typedef __attribute__((ext_vector_type(8))) _Float16 f16x8;
typedef __attribute__((ext_vector_type(4))) float f32x4;

__device__ __forceinline__ void async_load16(const void* g, void* lds) {
  __builtin_amdgcn_global_load_lds(
      (const __attribute__((address_space(1))) void*)g,
      (__attribute__((address_space(3))) void*)lds, 16, 0, 0);
}

__device__ __forceinline__ float fast_tanh(float x) {
  float a = fabsf(x);
  float e = __expf(-2.0f * a);
  float r = (1.0f - e) * __builtin_amdgcn_rcpf(1.0f + e);
  return copysignf(r, x);
}

// ---- CSR scan ----
__global__ __launch_bounds__(256) void scan_partial(const int* __restrict__ degi,
                                                    int* __restrict__ bsum, int N) {
  __shared__ int lds[256];
  int b = blockIdx.x, t = threadIdx.x;
  int s = 0;
#pragma unroll
  for (int j = 0; j < 4; ++j) {
    int idx = b * 1024 + t * 4 + j;
    if (idx < N) s += degi[idx];
  }
  lds[t] = s;
  __syncthreads();
  for (int off = 128; off > 0; off >>= 1) {
    if (t < off) lds[t] += lds[t + off];
    __syncthreads();
  }
  if (t == 0) bsum[b] = lds[0];
}

__global__ __launch_bounds__(256) void scan_final(
    const int* __restrict__ degi, const int* __restrict__ bsum,
    int* __restrict__ row_start, int* __restrict__ cursor, int nb, int N, int E) {
  __shared__ int lds[256];
  __shared__ int sboff;
  int b = blockIdx.x, t = threadIdx.x;
  lds[t] = (t < b && t < nb) ? bsum[t] : 0;
  __syncthreads();
  for (int off = 128; off > 0; off >>= 1) {
    if (t < off) lds[t] += lds[t + off];
    __syncthreads();
  }
  if (t == 0) {
    sboff = lds[0];
    if (b == 0) row_start[N] = E;
  }
  __syncthreads();

  int base = b * 1024;
  int v[4];
  int s = 0;
#pragma unroll
  for (int j = 0; j < 4; ++j) {
    int idx = base + t * 4 + j;
    v[j] = (idx < N) ? degi[idx] : 0;
    s += v[j];
  }
  lds[t] = s;
  __syncthreads();
  for (int off = 1; off < 256; off <<= 1) {
    int x = lds[t];
    int y = (t >= off) ? lds[t - off] : 0;
    __syncthreads();
    lds[t] = x + y;
    __syncthreads();
  }
  int pre = sboff + lds[t] - s;
#pragma unroll
  for (int j = 0; j < 4; ++j) {
    int idx = base + t * 4 + j;
    if (idx < N) { row_start[idx] = pre; cursor[idx] = pre; pre += v[j]; }
  }
}

__global__ __launch_bounds__(256) void fill_adj(const int* __restrict__ src,
                                                const int* __restrict__ dst,
                                                int* __restrict__ cursor,
                                                int* __restrict__ adj, int E) {
  int e = blockIdx.x * 256 + threadIdx.x;
  if (e >= E) return;
  int p = atomicAdd(&cursor[dst[e]], 1);
  adj[p] = src[e];
}

// ---- merged: deg_count + weight prep + z16 cast ----
__global__ __launch_bounds__(256) void fused_prep(
    const int* __restrict__ dst, int* __restrict__ degi, int E,
    const float* __restrict__ Wg, const float* __restrict__ Ws,
    const float* __restrict__ W1, const float* __restrict__ W2,
    const float* __restrict__ W3, f16* __restrict__ wgs, f16* __restrict__ wt1,
    f16* __restrict__ wt2, f16* __restrict__ wt3,
    const float* __restrict__ z, f16* __restrict__ z16, int n4) {
  int i0 = blockIdx.x * 256 + threadIdx.x;
  int stride = gridDim.x * 256;
  for (int i = i0; i < n4; i += stride) {
    float4 v = *(const float4*)(z + 4 * (long long)i);
    f16x4 c;
    c[0] = (f16)v.x; c[1] = (f16)v.y; c[2] = (f16)v.z; c[3] = (f16)v.w;
    *(f16x4*)(z16 + 4 * (long long)i) = c;
  }
  for (int i = i0; i < E; i += stride) atomicAdd(&degi[dst[i]], 1);
  for (int i = i0; i < 425984; i += stride) {
    if (i < 32768) {
      int n = i >> 8, k = i & 255;
      wgs[i] = (f16)((k < 128) ? Wg[k * 128 + n] : Ws[(k - 128) * 128 + n]);
    } else if (i < 98304) {
      int j = i - 32768, c = j >> 7, k = j & 127;
      wt1[j] = (f16)W1[k * 512 + c];
    } else if (i < 360448) {
      int j = i - 98304, c = j >> 9, k = j & 511;
      wt2[j] = (f16)W2[k * 512 + c];
    } else {
      int j = i - 360448, c = j >> 9, k = j & 511;
      wt3[j] = (f16)W3[k * 128 + c];
    }
  }
}

// ---- gather + mean -> Xm[node*128 + d]: 32 lanes/node, masked 8-wide ----
__global__ __launch_bounds__(256) void gather_xm(
    const f16* __restrict__ z16, const int* __restrict__ row_start,
    const int* __restrict__ adj, f16* __restrict__ Xm, int N) {
  int node = (blockIdx.x * 256 + threadIdx.x) >> 5;
  if (node >= N) return;
  int lane = threadIdx.x & 31;
  int beg = row_start[node], end = row_start[node + 1];
  float a0 = 0, a1 = 0, a2 = 0, a3 = 0;
#pragma unroll
  for (int j = 0; j < 8; ++j) {
    int idx = beg + j;
    bool vld = idx < end;
    int nb = adj[vld ? idx : beg];
    f16x4 x = *(const f16x4*)(z16 + (long long)nb * 128 + 4 * lane);
    float w = vld ? 1.0f : 0.0f;
    a0 += w * (float)x[0]; a1 += w * (float)x[1];
    a2 += w * (float)x[2]; a3 += w * (float)x[3];
  }
  int i = beg + 8;
  if (i < end) {
    float b0 = 0, b1 = 0, b2 = 0, b3 = 0;
    float c0 = 0, c1 = 0, c2 = 0, c3 = 0;
    float d0 = 0, d1 = 0, d2 = 0, d3 = 0;
    for (; i + 4 <= end; i += 4) {
      int n0 = adj[i], n1 = adj[i + 1], n2 = adj[i + 2], n3 = adj[i + 3];
      f16x4 v0 = *(const f16x4*)(z16 + (long long)n0 * 128 + 4 * lane);
      f16x4 v1 = *(const f16x4*)(z16 + (long long)n1 * 128 + 4 * lane);
      f16x4 v2 = *(const f16x4*)(z16 + (long long)n2 * 128 + 4 * lane);
      f16x4 v3 = *(const f16x4*)(z16 + (long long)n3 * 128 + 4 * lane);
      a0 += (float)v0[0]; a1 += (float)v0[1]; a2 += (float)v0[2]; a3 += (float)v0[3];
      b0 += (float)v1[0]; b1 += (float)v1[1]; b2 += (float)v1[2]; b3 += (float)v1[3];
      c0 += (float)v2[0]; c1 += (float)v2[1]; c2 += (float)v2[2]; c3 += (float)v2[3];
      d0 += (float)v3[0]; d1 += (float)v3[1]; d2 += (float)v3[2]; d3 += (float)v3[3];
    }
    for (; i < end; ++i) {
      f16x4 v = *(const f16x4*)(z16 + (long long)adj[i] * 128 + 4 * lane);
      a0 += (float)v[0]; a1 += (float)v[1]; a2 += (float)v[2]; a3 += (float)v[3];
    }
    a0 += b0 + c0 + d0; a1 += b1 + c1 + d1;
    a2 += b2 + c2 + d2; a3 += b3 + c3 + d3;
  }
  int dg = end - beg;
  float inv = 1.0f / (float)(dg > 1 ? dg : 1);
  f16x4 m;
  m[0] = (f16)(a0 * inv); m[1] = (f16)(a1 * inv);
  m[2] = (f16)(a2 * inv); m[3] = (f16)(a3 * inv);
  *(f16x4*)(Xm + (long long)node * 128 + 4 * lane) = m;
}

// ======================= fused L1+L2 (dual-source A staging) =======================
// A = [Xm | z16] picked by k0; LDS layout/swizzle identical to proven version.
__global__ __launch_bounds__(256) void fused12(
    const f16* __restrict__ Xm, const f16* __restrict__ z16,
    const f16* __restrict__ wgs, const f16* __restrict__ wt1,
    const float* __restrict__ bg, const float* __restrict__ b1,
    f16* __restrict__ h2) {
  __shared__ __align__(16) char L[49152];
  const int tid = threadIdx.x;
  const int wid = tid >> 6, lane = tid & 63;
  const int wm = wid & 1, wn = wid >> 1;  // 2x2
  const int lr = lane & 15, lq = lane >> 4;
  const int key = lr & 7;
  const long long m0 = (long long)blockIdx.x * 128;

  // per-thread A-stage offset (row stride 128 f16)
  long long aOff[4];
#pragma unroll
  for (int c = 0; c < 4; ++c) {
    int f = c * 256 + tid;
    int row = f >> 3, ss = (f & 7) ^ (row & 7);
    aOff[c] = (long long)row * 128 + ss * 8;
  }

  f32x4 acc[4][4];
#pragma unroll
  for (int i = 0; i < 4; ++i)
#pragma unroll
    for (int j = 0; j < 4; ++j)
#pragma unroll
      for (int r = 0; r < 4; ++r) acc[i][j][r] = 0.0f;

  // ---- phase 1: L1, K=256 over [Xm | z16] ----
#pragma unroll 1
  for (int k0 = 0; k0 < 256; k0 += 64) {
    const f16* Asrc = ((k0 < 128) ? Xm : z16) + m0 * 128 + (k0 & 127);
#pragma unroll
    for (int c = 0; c < 4; ++c) {
      int f = c * 256 + tid;
      async_load16(Asrc + aOff[c], L + f * 16);
    }
#pragma unroll
    for (int c = 0; c < 4; ++c) {
      int f = c * 256 + tid;
      int row = f >> 3, ss = (f & 7) ^ (row & 7);
      async_load16(wgs + row * 256 + k0 + ss * 8, L + 16384 + f * 16);
    }
    __syncthreads();
#pragma unroll
    for (int kk = 0; kk < 64; kk += 32) {
      const int co = (((kk >> 3) + lq) ^ key) * 16;
      f16x8 a[4], b[4];
#pragma unroll
      for (int i = 0; i < 4; ++i)
        a[i] = *reinterpret_cast<const f16x8*>(L + (wm * 64 + i * 16 + lr) * 128 + co);
#pragma unroll
      for (int j = 0; j < 4; ++j)
        b[j] = *reinterpret_cast<const f16x8*>(L + 16384 + (wn * 64 + j * 16 + lr) * 128 + co);
#pragma unroll
      for (int i = 0; i < 4; ++i)
#pragma unroll
        for (int j = 0; j < 4; ++j)
          acc[i][j] = __builtin_amdgcn_mfma_f32_16x16x32_f16(a[i], b[j], acc[i][j], 0, 0, 0);
    }
    __syncthreads();
  }

  // acc -> H1 (relu + bg), swizzled [128][128] f16 at L[0,32K)
#pragma unroll
  for (int i = 0; i < 4; ++i)
#pragma unroll
    for (int j = 0; j < 4; ++j) {
      int col = wn * 64 + j * 16 + lr;
      float bv = bg[col];
#pragma unroll
      for (int r = 0; r < 4; ++r) {
        int row = wm * 64 + i * 16 + lq * 4 + r;
        float v = fmaxf(acc[i][j][r] + bv, 0.0f);
        *reinterpret_cast<f16*>(L + row * 256 + (((col >> 3) ^ (row & 7)) * 16) +
                                (col & 7) * 2) = (f16)v;
      }
    }
  __syncthreads();

  // ---- phase 2: L2, K=128 (from H1), per 128-col block ----
#pragma unroll 1
  for (int cb = 0; cb < 4; ++cb) {
#pragma unroll
    for (int i = 0; i < 4; ++i)
#pragma unroll
      for (int j = 0; j < 4; ++j)
#pragma unroll
        for (int r = 0; r < 4; ++r) acc[i][j][r] = 0.0f;

#pragma unroll 1
    for (int kc = 0; kc < 2; ++kc) {
#pragma unroll
      for (int c = 0; c < 4; ++c) {
        int f = c * 256 + tid;
        int row = f >> 3, ss = (f & 7) ^ (row & 7);
        async_load16(wt1 + (long long)(cb * 128 + row) * 128 + kc * 64 + ss * 8,
                     L + 32768 + f * 16);
      }
      __syncthreads();
#pragma unroll
      for (int kk = 0; kk < 64; kk += 32) {
        const int aslot = kc * 8 + (kk >> 3) + lq;
        const int bco = (((kk >> 3) + lq) ^ key) * 16;
        f16x8 a[4], b[4];
#pragma unroll
        for (int i = 0; i < 4; ++i)
          a[i] = *reinterpret_cast<const f16x8*>(
              L + (wm * 64 + i * 16 + lr) * 256 + (aslot ^ key) * 16);
#pragma unroll
        for (int j = 0; j < 4; ++j)
          b[j] = *reinterpret_cast<const f16x8*>(
              L + 32768 + (wn * 64 + j * 16 + lr) * 128 + bco);
#pragma unroll
        for (int i = 0; i < 4; ++i)
#pragma unroll
          for (int j = 0; j < 4; ++j)
            acc[i][j] = __builtin_amdgcn_mfma_f32_16x16x32_f16(a[i], b[j], acc[i][j], 0, 0, 0);
      }
      __syncthreads();
    }
#pragma unroll
    for (int i = 0; i < 4; ++i)
#pragma unroll
      for (int j = 0; j < 4; ++j) {
        int colg = cb * 128 + wn * 64 + j * 16 + lr;
        float bv = b1[colg];
#pragma unroll
        for (int r = 0; r < 4; ++r) {
          long long row = m0 + wm * 64 + i * 16 + lq * 4 + r;
          h2[row * 512 + colg] = (f16)fast_tanh(acc[i][j][r] + bv);
        }
      }
  }
}

// --------- R5/R11 proven drain GEMM (BK=64, single buffer, swizzled) ----------
// SWZ=1: 1D grid, XCD-chunked remap so A-panel pairs land on one XCD.
template <int K, int NOUT, int WM, int WN, int MI, int ACT, bool OUTF32, int SWZ>
__global__ __launch_bounds__(WM * WN * 64) void gemm_r(
    const f16* __restrict__ X, const f16* __restrict__ Wt,
    const float* __restrict__ bias, void* __restrict__ OutV, int M) {
  constexpr int NJ = 4;
  constexpr int BM = WM * MI * 16;
  constexpr int BN = WN * NJ * 16;
  constexpr int NTHR = WM * WN * 64;
  constexpr int CA = (BM * 128) / (NTHR * 16);
  constexpr int CB = (BN * 128) / (NTHR * 16);
  __shared__ __align__(16) f16 As[BM * 64];
  __shared__ __align__(16) f16 Bs[BN * 64];

  const int tid = threadIdx.x;
  const int wid = tid >> 6, lane = tid & 63;
  const int wm = wid / WN, wn = wid % WN;
  const int lr = lane & 15, lq = lane >> 4;
  const int rxor = lr & 7;

  int bx, by;
  if constexpr (SWZ) {
    int bid = blockIdx.x;
    int wid2 = bid;
    if ((gridDim.x & 7) == 0) {
      int q = gridDim.x >> 3;
      wid2 = (bid & 7) * q + (bid >> 3);  // chunked per-XCD order
    }
    bx = wid2 >> 1;           // A-panel index
    by = wid2 & 1;            // column half; pair (bx,0),(bx,1) adjacent per XCD
  } else {
    bx = blockIdx.x; by = blockIdx.y;
  }
  const long long m0 = (long long)bx * BM;
  const int n0 = by * BN;

  const f16* Ag = X + m0 * K;
  const f16* Bg = Wt + (long long)n0 * K;

  long long aOff[CA], bOff[CB];
#pragma unroll
  for (int c = 0; c < CA; ++c) {
    int f = c * NTHR + tid;
    int row = f >> 3, ss = (f & 7) ^ (row & 7);
    aOff[c] = (long long)row * K + ss * 8;
  }
#pragma unroll
  for (int c = 0; c < CB; ++c) {
    int f = c * NTHR + tid;
    int row = f >> 3, ss = (f & 7) ^ (row & 7);
    bOff[c] = (long long)row * K + ss * 8;
  }

  f32x4 acc[MI][NJ];
#pragma unroll
  for (int i = 0; i < MI; ++i)
#pragma unroll
    for (int j = 0; j < NJ; ++j)
#pragma unroll
      for (int r = 0; r < 4; ++r) acc[i][j][r] = 0.0f;

#pragma unroll 1
  for (int k0 = 0; k0 < K; k0 += 64) {
#pragma unroll
    for (int c = 0; c < CA; ++c)
      async_load16(Ag + aOff[c] + k0, (char*)As + c * NTHR * 16 + wid * 1024);
#pragma unroll
    for (int c = 0; c < CB; ++c)
      async_load16(Bg + bOff[c] + k0, (char*)Bs + c * NTHR * 16 + wid * 1024);
    __syncthreads();
#pragma unroll
    for (int kk = 0; kk < 64; kk += 32) {
      const int co = (((kk >> 3) + lq) ^ rxor) * 16;
      f16x8 a[MI], b[NJ];
#pragma unroll
      for (int i = 0; i < MI; ++i)
        a[i] = *reinterpret_cast<const f16x8*>(
            (const char*)As + (wm * MI * 16 + i * 16 + lr) * 128 + co);
#pragma unroll
      for (int j = 0; j < NJ; ++j)
        b[j] = *reinterpret_cast<const f16x8*>(
            (const char*)Bs + (wn * NJ * 16 + j * 16 + lr) * 128 + co);
#pragma unroll
      for (int i = 0; i < MI; ++i)
#pragma unroll
        for (int j = 0; j < NJ; ++j)
          acc[i][j] = __builtin_amdgcn_mfma_f32_16x16x32_f16(a[i], b[j], acc[i][j], 0, 0, 0);
    }
    __syncthreads();
  }

#pragma unroll
  for (int i = 0; i < MI; ++i) {
#pragma unroll
    for (int j = 0; j < NJ; ++j) {
      int col = n0 + wn * NJ * 16 + j * 16 + lr;
      float bv = bias[col];
#pragma unroll
      for (int r = 0; r < 4; ++r) {
        long long row = m0 + wm * MI * 16 + i * 16 + lq * 4 + r;
        if (row < M) {
          float v = acc[i][j][r] + bv;
          if (ACT == 1) v = fmaxf(v, 0.0f);
          else if (ACT == 2) v = fast_tanh(v);
          if constexpr (OUTF32)
            ((float*)OutV)[row * NOUT + col] = v;
          else
            ((f16*)OutV)[row * NOUT + col] = (f16)v;
        }
      }
    }
  }
}

extern "C" void kernel_launch(void* const* d_in, const int* in_sizes, int n_in,
                              void* d_out, int out_size, void* d_ws, size_t ws_size,
                              hipStream_t stream) {
  const float* z  = (const float*)d_in[0];
  const int*   ei = (const int*)d_in[1];
  const float* Wg = (const float*)d_in[2];
  const float* Ws = (const float*)d_in[3];
  const float* bg = (const float*)d_in[4];
  const float* W1 = (const float*)d_in[5];
  const float* b1 = (const float*)d_in[6];
  const float* W2 = (const float*)d_in[7];
  const float* b2 = (const float*)d_in[8];
  const float* W3 = (const float*)d_in[9];
  const float* b3 = (const float*)d_in[10];

  const int Nn = in_sizes[0] / 128;
  const int E  = in_sizes[1] / 2;
  const int* src = ei;
  const int* dst = ei + E;
  const int nb = (Nn + 1023) / 1024;
  const int gm256 = (Nn + 255) / 256;        // 256-row tiles (gemm4)
  const long long Mpad = (long long)gm256 * 256;
  const int gm128 = gm256 * 2;               // 128-row tiles (fused12, gemm3)

  // workspace overlay (peak ~207 MB):
  //   [0, 25.6M)        Xm    (gather -> fused12)
  //   [25.6, 51.2M)     z16   (prep -> gather, fused12)
  //   [51.2, ~81M)      CSR   (dead after gather)
  //   [0, 102.4M)       h3    (gemm3 -> gemm4; overlays Xm+z16+CSR, all dead)
  //   [102.4, 204.8M)   h2    (fused12 -> gemm3)
  //   [204.8M, ...)     prepped weights (~1.7 MB)
  char* base = (char*)d_ws;
  const size_t XMB = (size_t)Mpad * 128 * 2;
  const size_t H3B = (size_t)Mpad * 512 * 2;
  f16* Xm  = (f16*)(base);
  f16* h3  = (f16*)(base);
  f16* z16 = (f16*)(base + XMB);
  size_t off = XMB + (size_t)Mpad * 128 * 2;  // after z16 span
  auto alloc = [&](size_t b) -> void* {
    void* p = base + off;
    off += (b + 255) & ~(size_t)255;
    return p;
  };
  int* degi      = (int*)alloc((size_t)Nn * 4);
  int* row_start = (int*)alloc((size_t)(Nn + 1) * 4);
  int* cursor    = (int*)alloc((size_t)Nn * 4);
  int* adj       = (int*)alloc((size_t)(E + 8) * 4);
  int* bsum      = (int*)alloc((size_t)nb * 4);
  off = H3B;  // h2 after h3 span
  f16* h2  = (f16*)alloc((size_t)Mpad * 512 * 2);
  f16* wgs = (f16*)alloc((size_t)128 * 256 * 2);
  f16* wt1 = (f16*)alloc((size_t)512 * 128 * 2);
  f16* wt2 = (f16*)alloc((size_t)512 * 512 * 2);
  f16* wt3 = (f16*)alloc((size_t)128 * 512 * 2);

  // CSR + prep
  hipMemsetAsync(degi, 0, (size_t)Nn * 4, stream);
  fused_prep<<<2048, 256, 0, stream>>>(dst, degi, E, Wg, Ws, W1, W2, W3,
                                       wgs, wt1, wt2, wt3, z, z16, Nn * 32);
  scan_partial<<<nb, 256, 0, stream>>>(degi, bsum, Nn);
  scan_final<<<nb, 256, 0, stream>>>(degi, bsum, row_start, cursor, nb, Nn, E);
  fill_adj<<<(E + 255) / 256, 256, 0, stream>>>(src, dst, cursor, adj, E);

  // gather mean -> Xm
  {
    long long tot = (long long)Nn * 32;
    gather_xm<<<(int)((tot + 255) / 256), 256, 0, stream>>>(z16, row_start, adj, Xm, Nn);
  }

  // MLP: fused L1+L2 (dual-source A); gemm3 XCD-paired 1D grid; gemm4 as R18.
  fused12<<<gm128, 256, 0, stream>>>(Xm, z16, wgs, wt1, bg, b1, h2);
  gemm_r<512, 512, 2, 4, 4, 2, false, 1><<<gm128 * 2, 512, 0, stream>>>(h2, wt2, b2, (void*)h3, Nn);
  gemm_r<512, 128, 4, 1, 4, 0, true, 0><<<dim3(gm256, 2), 256, 0, stream>>>(h3, wt3, b3, d_out, Nn);
}

// Round 20
// 300.889 us; speedup vs baseline: 1.1558x; 1.1558x over previous
//
#include <hip/hip_runtime.h>
#include <hip/hip_fp16.h>

// GDE func: out = MLP(relu(mean_agg(z,edges)@Wg + z@Ws + bg))
// Round 19 -> 20: revert fused12/prep/gather to exact R17 proven versions
// (dual-source A staging collapsed fused12 to 8.9% occupancy / 107us).
// Keep gemm3's 1D paired launch from R19 (ledger suggests it helped:
// (bx,0),(bx,1) adjacent -> A-panel L2/L3 reuse). Single uncertain element.

typedef _Float16 f16;
typedef __attribute__((ext_vector_type(4))) _Float16 f16x4;
typedef __attribute__((ext_vector_type(8))) _Float16 f16x8;
typedef __attribute__((ext_vector_type(4))) float f32x4;

__device__ __forceinline__ void async_load16(const void* g, void* lds) {
  __builtin_amdgcn_global_load_lds(
      (const __attribute__((address_space(1))) void*)g,
      (__attribute__((address_space(3))) void*)lds, 16, 0, 0);
}

__device__ __forceinline__ float fast_tanh(float x) {
  float a = fabsf(x);
  float e = __expf(-2.0f * a);
  float r = (1.0f - e) * __builtin_amdgcn_rcpf(1.0f + e);
  return copysignf(r, x);
}

// ---- CSR scan ----
__global__ __launch_bounds__(256) void scan_partial(const int* __restrict__ degi,
                                                    int* __restrict__ bsum, int N) {
  __shared__ int lds[256];
  int b = blockIdx.x, t = threadIdx.x;
  int s = 0;
#pragma unroll
  for (int j = 0; j < 4; ++j) {
    int idx = b * 1024 + t * 4 + j;
    if (idx < N) s += degi[idx];
  }
  lds[t] = s;
  __syncthreads();
  for (int off = 128; off > 0; off >>= 1) {
    if (t < off) lds[t] += lds[t + off];
    __syncthreads();
  }
  if (t == 0) bsum[b] = lds[0];
}

__global__ __launch_bounds__(256) void scan_final(
    const int* __restrict__ degi, const int* __restrict__ bsum,
    int* __restrict__ row_start, int* __restrict__ cursor, int nb, int N, int E) {
  __shared__ int lds[256];
  __shared__ int sboff;
  int b = blockIdx.x, t = threadIdx.x;
  lds[t] = (t < b && t < nb) ? bsum[t] : 0;
  __syncthreads();
  for (int off = 128; off > 0; off >>= 1) {
    if (t < off) lds[t] += lds[t + off];
    __syncthreads();
  }
  if (t == 0) {
    sboff = lds[0];
    if (b == 0) row_start[N] = E;
  }
  __syncthreads();

  int base = b * 1024;
  int v[4];
  int s = 0;
#pragma unroll
  for (int j = 0; j < 4; ++j) {
    int idx = base + t * 4 + j;
    v[j] = (idx < N) ? degi[idx] : 0;
    s += v[j];
  }
  lds[t] = s;
  __syncthreads();
  for (int off = 1; off < 256; off <<= 1) {
    int x = lds[t];
    int y = (t >= off) ? lds[t - off] : 0;
    __syncthreads();
    lds[t] = x + y;
    __syncthreads();
  }
  int pre = sboff + lds[t] - s;
#pragma unroll
  for (int j = 0; j < 4; ++j) {
    int idx = base + t * 4 + j;
    if (idx < N) { row_start[idx] = pre; cursor[idx] = pre; pre += v[j]; }
  }
}

__global__ __launch_bounds__(256) void fill_adj(const int* __restrict__ src,
                                                const int* __restrict__ dst,
                                                int* __restrict__ cursor,
                                                int* __restrict__ adj, int E) {
  int e = blockIdx.x * 256 + threadIdx.x;
  if (e >= E) return;
  int p = atomicAdd(&cursor[dst[e]], 1);
  adj[p] = src[e];
}

// ---- merged: deg_count + weight prep + z16 cast (+Xc z-half) ----
__global__ __launch_bounds__(256) void fused_prep(
    const int* __restrict__ dst, int* __restrict__ degi, int E,
    const float* __restrict__ Wg, const float* __restrict__ Ws,
    const float* __restrict__ W1, const float* __restrict__ W2,
    const float* __restrict__ W3, f16* __restrict__ wgs, f16* __restrict__ wt1,
    f16* __restrict__ wt2, f16* __restrict__ wt3,
    const float* __restrict__ z, f16* __restrict__ z16, f16* __restrict__ Xc,
    int n4) {
  int i0 = blockIdx.x * 256 + threadIdx.x;
  int stride = gridDim.x * 256;
  for (int i = i0; i < n4; i += stride) {
    float4 v = *(const float4*)(z + 4 * (long long)i);
    f16x4 c;
    c[0] = (f16)v.x; c[1] = (f16)v.y; c[2] = (f16)v.z; c[3] = (f16)v.w;
    *(f16x4*)(z16 + 4 * (long long)i) = c;
    int node = i >> 5, sl = i & 31;
    *(f16x4*)(Xc + (long long)node * 256 + 128 + 4 * sl) = c;
  }
  for (int i = i0; i < E; i += stride) atomicAdd(&degi[dst[i]], 1);
  for (int i = i0; i < 425984; i += stride) {
    if (i < 32768) {
      int n = i >> 8, k = i & 255;
      wgs[i] = (f16)((k < 128) ? Wg[k * 128 + n] : Ws[(k - 128) * 128 + n]);
    } else if (i < 98304) {
      int j = i - 32768, c = j >> 7, k = j & 127;
      wt1[j] = (f16)W1[k * 512 + c];
    } else if (i < 360448) {
      int j = i - 98304, c = j >> 9, k = j & 511;
      wt2[j] = (f16)W2[k * 512 + c];
    } else {
      int j = i - 360448, c = j >> 9, k = j & 511;
      wt3[j] = (f16)W3[k * 128 + c];
    }
  }
}

// ---- gather + mean -> Xc mean-half: 32 lanes/node, masked 8-wide batch ----
__global__ __launch_bounds__(256) void gather_xcat(
    const f16* __restrict__ z16, const int* __restrict__ row_start,
    const int* __restrict__ adj, f16* __restrict__ Xc, int N) {
  int node = (blockIdx.x * 256 + threadIdx.x) >> 5;
  if (node >= N) return;
  int lane = threadIdx.x & 31;
  int beg = row_start[node], end = row_start[node + 1];
  float a0 = 0, a1 = 0, a2 = 0, a3 = 0;
#pragma unroll
  for (int j = 0; j < 8; ++j) {
    int idx = beg + j;
    bool vld = idx < end;
    int nb = adj[vld ? idx : beg];
    f16x4 x = *(const f16x4*)(z16 + (long long)nb * 128 + 4 * lane);
    float w = vld ? 1.0f : 0.0f;
    a0 += w * (float)x[0]; a1 += w * (float)x[1];
    a2 += w * (float)x[2]; a3 += w * (float)x[3];
  }
  int i = beg + 8;
  if (i < end) {
    float b0 = 0, b1 = 0, b2 = 0, b3 = 0;
    float c0 = 0, c1 = 0, c2 = 0, c3 = 0;
    float d0 = 0, d1 = 0, d2 = 0, d3 = 0;
    for (; i + 4 <= end; i += 4) {
      int n0 = adj[i], n1 = adj[i + 1], n2 = adj[i + 2], n3 = adj[i + 3];
      f16x4 v0 = *(const f16x4*)(z16 + (long long)n0 * 128 + 4 * lane);
      f16x4 v1 = *(const f16x4*)(z16 + (long long)n1 * 128 + 4 * lane);
      f16x4 v2 = *(const f16x4*)(z16 + (long long)n2 * 128 + 4 * lane);
      f16x4 v3 = *(const f16x4*)(z16 + (long long)n3 * 128 + 4 * lane);
      a0 += (float)v0[0]; a1 += (float)v0[1]; a2 += (float)v0[2]; a3 += (float)v0[3];
      b0 += (float)v1[0]; b1 += (float)v1[1]; b2 += (float)v1[2]; b3 += (float)v1[3];
      c0 += (float)v2[0]; c1 += (float)v2[1]; c2 += (float)v2[2]; c3 += (float)v2[3];
      d0 += (float)v3[0]; d1 += (float)v3[1]; d2 += (float)v3[2]; d3 += (float)v3[3];
    }
    for (; i < end; ++i) {
      f16x4 v = *(const f16x4*)(z16 + (long long)adj[i] * 128 + 4 * lane);
      a0 += (float)v[0]; a1 += (float)v[1]; a2 += (float)v[2]; a3 += (float)v[3];
    }
    a0 += b0 + c0 + d0; a1 += b1 + c1 + d1;
    a2 += b2 + c2 + d2; a3 += b3 + c3 + d3;
  }
  int dg = end - beg;
  float inv = 1.0f / (float)(dg > 1 ? dg : 1);
  long long o = (long long)node * 256;
  f16x4 m;
  m[0] = (f16)(a0 * inv); m[1] = (f16)(a1 * inv);
  m[2] = (f16)(a2 * inv); m[3] = (f16)(a3 * inv);
  *(f16x4*)(Xc + o + 4 * lane) = m;
}

// ======================= fused L1+L2 (exact R17 proven version) =======================
__global__ __launch_bounds__(256) void fused12(
    const f16* __restrict__ Xc, const f16* __restrict__ wgs,
    const f16* __restrict__ wt1, const float* __restrict__ bg,
    const float* __restrict__ b1, f16* __restrict__ h2) {
  __shared__ __align__(16) char L[49152];
  const int tid = threadIdx.x;
  const int wid = tid >> 6, lane = tid & 63;
  const int wm = wid & 1, wn = wid >> 1;  // 2x2
  const int lr = lane & 15, lq = lane >> 4;
  const int key = lr & 7;
  const long long m0 = (long long)blockIdx.x * 128;
  const f16* Ag = Xc + m0 * 256;

  f32x4 acc[4][4];
#pragma unroll
  for (int i = 0; i < 4; ++i)
#pragma unroll
    for (int j = 0; j < 4; ++j)
#pragma unroll
      for (int r = 0; r < 4; ++r) acc[i][j][r] = 0.0f;

#pragma unroll 1
  for (int k0 = 0; k0 < 256; k0 += 64) {
#pragma unroll
    for (int c = 0; c < 4; ++c) {
      int f = c * 256 + tid;
      int row = f >> 3, ss = (f & 7) ^ (row & 7);
      async_load16(Ag + (long long)row * 256 + k0 + ss * 8, L + f * 16);
    }
#pragma unroll
    for (int c = 0; c < 4; ++c) {
      int f = c * 256 + tid;
      int row = f >> 3, ss = (f & 7) ^ (row & 7);
      async_load16(wgs + row * 256 + k0 + ss * 8, L + 16384 + f * 16);
    }
    __syncthreads();
#pragma unroll
    for (int kk = 0; kk < 64; kk += 32) {
      const int co = (((kk >> 3) + lq) ^ key) * 16;
      f16x8 a[4], b[4];
#pragma unroll
      for (int i = 0; i < 4; ++i)
        a[i] = *reinterpret_cast<const f16x8*>(L + (wm * 64 + i * 16 + lr) * 128 + co);
#pragma unroll
      for (int j = 0; j < 4; ++j)
        b[j] = *reinterpret_cast<const f16x8*>(L + 16384 + (wn * 64 + j * 16 + lr) * 128 + co);
#pragma unroll
      for (int i = 0; i < 4; ++i)
#pragma unroll
        for (int j = 0; j < 4; ++j)
          acc[i][j] = __builtin_amdgcn_mfma_f32_16x16x32_f16(a[i], b[j], acc[i][j], 0, 0, 0);
    }
    __syncthreads();
  }

#pragma unroll
  for (int i = 0; i < 4; ++i)
#pragma unroll
    for (int j = 0; j < 4; ++j) {
      int col = wn * 64 + j * 16 + lr;
      float bv = bg[col];
#pragma unroll
      for (int r = 0; r < 4; ++r) {
        int row = wm * 64 + i * 16 + lq * 4 + r;
        float v = fmaxf(acc[i][j][r] + bv, 0.0f);
        *reinterpret_cast<f16*>(L + row * 256 + (((col >> 3) ^ (row & 7)) * 16) +
                                (col & 7) * 2) = (f16)v;
      }
    }
  __syncthreads();

#pragma unroll 1
  for (int cb = 0; cb < 4; ++cb) {
#pragma unroll
    for (int i = 0; i < 4; ++i)
#pragma unroll
      for (int j = 0; j < 4; ++j)
#pragma unroll
        for (int r = 0; r < 4; ++r) acc[i][j][r] = 0.0f;

#pragma unroll 1
    for (int kc = 0; kc < 2; ++kc) {
#pragma unroll
      for (int c = 0; c < 4; ++c) {
        int f = c * 256 + tid;
        int row = f >> 3, ss = (f & 7) ^ (row & 7);
        async_load16(wt1 + (long long)(cb * 128 + row) * 128 + kc * 64 + ss * 8,
                     L + 32768 + f * 16);
      }
      __syncthreads();
#pragma unroll
      for (int kk = 0; kk < 64; kk += 32) {
        const int aslot = kc * 8 + (kk >> 3) + lq;
        const int bco = (((kk >> 3) + lq) ^ key) * 16;
        f16x8 a[4], b[4];
#pragma unroll
        for (int i = 0; i < 4; ++i)
          a[i] = *reinterpret_cast<const f16x8*>(
              L + (wm * 64 + i * 16 + lr) * 256 + (aslot ^ key) * 16);
#pragma unroll
        for (int j = 0; j < 4; ++j)
          b[j] = *reinterpret_cast<const f16x8*>(
              L + 32768 + (wn * 64 + j * 16 + lr) * 128 + bco);
#pragma unroll
        for (int i = 0; i < 4; ++i)
#pragma unroll
          for (int j = 0; j < 4; ++j)
            acc[i][j] = __builtin_amdgcn_mfma_f32_16x16x32_f16(a[i], b[j], acc[i][j], 0, 0, 0);
      }
      __syncthreads();
    }
#pragma unroll
    for (int i = 0; i < 4; ++i)
#pragma unroll
      for (int j = 0; j < 4; ++j) {
        int colg = cb * 128 + wn * 64 + j * 16 + lr;
        float bv = b1[colg];
#pragma unroll
        for (int r = 0; r < 4; ++r) {
          long long row = m0 + wm * 64 + i * 16 + lq * 4 + r;
          h2[row * 512 + colg] = (f16)fast_tanh(acc[i][j][r] + bv);
        }
      }
  }
}

// --------- R5/R11 proven drain GEMM (BK=64, single buffer, swizzled) ----------
// SWZ=1: 1D grid, (bx,0),(bx,1) adjacent -> A-panel reuse (R19 variant).
template <int K, int NOUT, int WM, int WN, int MI, int ACT, bool OUTF32, int SWZ>
__global__ __launch_bounds__(WM * WN * 64) void gemm_r(
    const f16* __restrict__ X, const f16* __restrict__ Wt,
    const float* __restrict__ bias, void* __restrict__ OutV, int M) {
  constexpr int NJ = 4;
  constexpr int BM = WM * MI * 16;
  constexpr int BN = WN * NJ * 16;
  constexpr int NTHR = WM * WN * 64;
  constexpr int CA = (BM * 128) / (NTHR * 16);
  constexpr int CB = (BN * 128) / (NTHR * 16);
  __shared__ __align__(16) f16 As[BM * 64];
  __shared__ __align__(16) f16 Bs[BN * 64];

  const int tid = threadIdx.x;
  const int wid = tid >> 6, lane = tid & 63;
  const int wm = wid / WN, wn = wid % WN;
  const int lr = lane & 15, lq = lane >> 4;
  const int rxor = lr & 7;

  int bx, by;
  if constexpr (SWZ) {
    int bid = blockIdx.x;
    int wid2 = bid;
    if ((gridDim.x & 7) == 0) {
      int q = gridDim.x >> 3;
      wid2 = (bid & 7) * q + (bid >> 3);
    }
    bx = wid2 >> 1;
    by = wid2 & 1;
  } else {
    bx = blockIdx.x; by = blockIdx.y;
  }
  const long long m0 = (long long)bx * BM;
  const int n0 = by * BN;

  const f16* Ag = X + m0 * K;
  const f16* Bg = Wt + (long long)n0 * K;

  long long aOff[CA], bOff[CB];
#pragma unroll
  for (int c = 0; c < CA; ++c) {
    int f = c * NTHR + tid;
    int row = f >> 3, ss = (f & 7) ^ (row & 7);
    aOff[c] = (long long)row * K + ss * 8;
  }
#pragma unroll
  for (int c = 0; c < CB; ++c) {
    int f = c * NTHR + tid;
    int row = f >> 3, ss = (f & 7) ^ (row & 7);
    bOff[c] = (long long)row * K + ss * 8;
  }

  f32x4 acc[MI][NJ];
#pragma unroll
  for (int i = 0; i < MI; ++i)
#pragma unroll
    for (int j = 0; j < NJ; ++j)
#pragma unroll
      for (int r = 0; r < 4; ++r) acc[i][j][r] = 0.0f;

#pragma unroll 1
  for (int k0 = 0; k0 < K; k0 += 64) {
#pragma unroll
    for (int c = 0; c < CA; ++c)
      async_load16(Ag + aOff[c] + k0, (char*)As + c * NTHR * 16 + wid * 1024);
#pragma unroll
    for (int c = 0; c < CB; ++c)
      async_load16(Bg + bOff[c] + k0, (char*)Bs + c * NTHR * 16 + wid * 1024);
    __syncthreads();
#pragma unroll
    for (int kk = 0; kk < 64; kk += 32) {
      const int co = (((kk >> 3) + lq) ^ rxor) * 16;
      f16x8 a[MI], b[NJ];
#pragma unroll
      for (int i = 0; i < MI; ++i)
        a[i] = *reinterpret_cast<const f16x8*>(
            (const char*)As + (wm * MI * 16 + i * 16 + lr) * 128 + co);
#pragma unroll
      for (int j = 0; j < NJ; ++j)
        b[j] = *reinterpret_cast<const f16x8*>(
            (const char*)Bs + (wn * NJ * 16 + j * 16 + lr) * 128 + co);
#pragma unroll
      for (int i = 0; i < MI; ++i)
#pragma unroll
        for (int j = 0; j < NJ; ++j)
          acc[i][j] = __builtin_amdgcn_mfma_f32_16x16x32_f16(a[i], b[j], acc[i][j], 0, 0, 0);
    }
    __syncthreads();
  }

#pragma unroll
  for (int i = 0; i < MI; ++i) {
#pragma unroll
    for (int j = 0; j < NJ; ++j) {
      int col = n0 + wn * NJ * 16 + j * 16 + lr;
      float bv = bias[col];
#pragma unroll
      for (int r = 0; r < 4; ++r) {
        long long row = m0 + wm * MI * 16 + i * 16 + lq * 4 + r;
        if (row < M) {
          float v = acc[i][j][r] + bv;
          if (ACT == 1) v = fmaxf(v, 0.0f);
          else if (ACT == 2) v = fast_tanh(v);
          if constexpr (OUTF32)
            ((float*)OutV)[row * NOUT + col] = v;
          else
            ((f16*)OutV)[row * NOUT + col] = (f16)v;
        }
      }
    }
  }
}

extern "C" void kernel_launch(void* const* d_in, const int* in_sizes, int n_in,
                              void* d_out, int out_size, void* d_ws, size_t ws_size,
                              hipStream_t stream) {
  const float* z  = (const float*)d_in[0];
  const int*   ei = (const int*)d_in[1];
  const float* Wg = (const float*)d_in[2];
  const float* Ws = (const float*)d_in[3];
  const float* bg = (const float*)d_in[4];
  const float* W1 = (const float*)d_in[5];
  const float* b1 = (const float*)d_in[6];
  const float* W2 = (const float*)d_in[7];
  const float* b2 = (const float*)d_in[8];
  const float* W3 = (const float*)d_in[9];
  const float* b3 = (const float*)d_in[10];

  const int Nn = in_sizes[0] / 128;
  const int E  = in_sizes[1] / 2;
  const int* src = ei;
  const int* dst = ei + E;
  const int nb = (Nn + 1023) / 1024;
  const int gm256 = (Nn + 255) / 256;
  const long long Mpad = (long long)gm256 * 256;
  const int gm128 = gm256 * 2;

  // workspace overlay (peak ~207 MB), R17 layout:
  //   [0, 51.2M)        Xc    (prep/gather -> fused12)
  //   [51.2, ~81M)      CSR + z16 (dead after gather)
  //   [0, 102.4M)       h3    (gemm3 -> gemm4; overlays Xc+CSR+z16)
  //   [102.4, 204.8M)   h2    (fused12 -> gemm3)
  //   [204.8M, ...)     prepped weights (~1.7 MB)
  char* base = (char*)d_ws;
  const size_t XCB = (size_t)Mpad * 256 * 2;
  const size_t H3B = (size_t)Mpad * 512 * 2;
  f16* Xc = (f16*)(base);
  f16* h3 = (f16*)(base);
  size_t off = XCB;
  auto alloc = [&](size_t b) -> void* {
    void* p = base + off;
    off += (b + 255) & ~(size_t)255;
    return p;
  };
  int* degi      = (int*)alloc((size_t)Nn * 4);
  int* row_start = (int*)alloc((size_t)(Nn + 1) * 4);
  int* cursor    = (int*)alloc((size_t)Nn * 4);
  int* adj       = (int*)alloc((size_t)(E + 8) * 4);
  int* bsum      = (int*)alloc((size_t)nb * 4);
  f16* z16       = (f16*)alloc((size_t)Nn * 128 * 2);
  off = H3B;
  f16* h2  = (f16*)alloc((size_t)Mpad * 512 * 2);
  f16* wgs = (f16*)alloc((size_t)128 * 256 * 2);
  f16* wt1 = (f16*)alloc((size_t)512 * 128 * 2);
  f16* wt2 = (f16*)alloc((size_t)512 * 512 * 2);
  f16* wt3 = (f16*)alloc((size_t)128 * 512 * 2);

  // CSR + prep
  hipMemsetAsync(degi, 0, (size_t)Nn * 4, stream);
  fused_prep<<<2048, 256, 0, stream>>>(dst, degi, E, Wg, Ws, W1, W2, W3,
                                       wgs, wt1, wt2, wt3, z, z16, Xc, Nn * 32);
  scan_partial<<<nb, 256, 0, stream>>>(degi, bsum, Nn);
  scan_final<<<nb, 256, 0, stream>>>(degi, bsum, row_start, cursor, nb, Nn, E);
  fill_adj<<<(E + 255) / 256, 256, 0, stream>>>(src, dst, cursor, adj, E);

  // gather mean-half
  {
    long long tot = (long long)Nn * 32;
    gather_xcat<<<(int)((tot + 255) / 256), 256, 0, stream>>>(z16, row_start, adj, Xc, Nn);
  }

  // MLP: fused L1+L2 (R17); gemm3 1D paired launch (R19); gemm4 (R17).
  fused12<<<gm128, 256, 0, stream>>>(Xc, wgs, wt1, bg, b1, h2);
  gemm_r<512, 512, 2, 4, 4, 2, false, 1><<<gm128 * 2, 512, 0, stream>>>(h2, wt2, b2, (void*)h3, Nn);
  gemm_r<512, 128, 4, 2, 4, 0, true, 0><<<dim3(gm256, 1), 512, 0, stream>>>(h3, wt3, b3, d_out, Nn);
}

// Round 21
// 300.323 us; speedup vs baseline: 1.1580x; 1.0019x over previous
//
#include <hip/hip_runtime.h>
#include <hip/hip_fp16.h>

// GDE func: out = MLP(relu(mean_agg(z,edges)@Wg + z@Ws + bg))
// Round 20 -> 21: single change — gather uses 16 lanes/node with f16x8
// (16B/lane) loads: same 256B/row coalescing, half the memory instructions
// and waves (latency-bound kernel, fixed 8-load window). Everything else
// frozen at R20 best (300.9us): gemm3 1D-paired drain GEMM, R17 fused12,
// fused_prep, CSR trims, gemm4 <4,2>.

typedef _Float16 f16;
typedef __attribute__((ext_vector_type(4))) _Float16 f16x4;
typedef __attribute__((ext_vector_type(8))) _Float16 f16x8;
typedef __attribute__((ext_vector_type(4))) float f32x4;

__device__ __forceinline__ void async_load16(const void* g, void* lds) {
  __builtin_amdgcn_global_load_lds(
      (const __attribute__((address_space(1))) void*)g,
      (__attribute__((address_space(3))) void*)lds, 16, 0, 0);
}

__device__ __forceinline__ float fast_tanh(float x) {
  float a = fabsf(x);
  float e = __expf(-2.0f * a);
  float r = (1.0f - e) * __builtin_amdgcn_rcpf(1.0f + e);
  return copysignf(r, x);
}

// ---- CSR scan ----
__global__ __launch_bounds__(256) void scan_partial(const int* __restrict__ degi,
                                                    int* __restrict__ bsum, int N) {
  __shared__ int lds[256];
  int b = blockIdx.x, t = threadIdx.x;
  int s = 0;
#pragma unroll
  for (int j = 0; j < 4; ++j) {
    int idx = b * 1024 + t * 4 + j;
    if (idx < N) s += degi[idx];
  }
  lds[t] = s;
  __syncthreads();
  for (int off = 128; off > 0; off >>= 1) {
    if (t < off) lds[t] += lds[t + off];
    __syncthreads();
  }
  if (t == 0) bsum[b] = lds[0];
}

__global__ __launch_bounds__(256) void scan_final(
    const int* __restrict__ degi, const int* __restrict__ bsum,
    int* __restrict__ row_start, int* __restrict__ cursor, int nb, int N, int E) {
  __shared__ int lds[256];
  __shared__ int sboff;
  int b = blockIdx.x, t = threadIdx.x;
  lds[t] = (t < b && t < nb) ? bsum[t] : 0;
  __syncthreads();
  for (int off = 128; off > 0; off >>= 1) {
    if (t < off) lds[t] += lds[t + off];
    __syncthreads();
  }
  if (t == 0) {
    sboff = lds[0];
    if (b == 0) row_start[N] = E;
  }
  __syncthreads();

  int base = b * 1024;
  int v[4];
  int s = 0;
#pragma unroll
  for (int j = 0; j < 4; ++j) {
    int idx = base + t * 4 + j;
    v[j] = (idx < N) ? degi[idx] : 0;
    s += v[j];
  }
  lds[t] = s;
  __syncthreads();
  for (int off = 1; off < 256; off <<= 1) {
    int x = lds[t];
    int y = (t >= off) ? lds[t - off] : 0;
    __syncthreads();
    lds[t] = x + y;
    __syncthreads();
  }
  int pre = sboff + lds[t] - s;
#pragma unroll
  for (int j = 0; j < 4; ++j) {
    int idx = base + t * 4 + j;
    if (idx < N) { row_start[idx] = pre; cursor[idx] = pre; pre += v[j]; }
  }
}

__global__ __launch_bounds__(256) void fill_adj(const int* __restrict__ src,
                                                const int* __restrict__ dst,
                                                int* __restrict__ cursor,
                                                int* __restrict__ adj, int E) {
  int e = blockIdx.x * 256 + threadIdx.x;
  if (e >= E) return;
  int p = atomicAdd(&cursor[dst[e]], 1);
  adj[p] = src[e];
}

// ---- merged: deg_count + weight prep + z16 cast (+Xc z-half) ----
__global__ __launch_bounds__(256) void fused_prep(
    const int* __restrict__ dst, int* __restrict__ degi, int E,
    const float* __restrict__ Wg, const float* __restrict__ Ws,
    const float* __restrict__ W1, const float* __restrict__ W2,
    const float* __restrict__ W3, f16* __restrict__ wgs, f16* __restrict__ wt1,
    f16* __restrict__ wt2, f16* __restrict__ wt3,
    const float* __restrict__ z, f16* __restrict__ z16, f16* __restrict__ Xc,
    int n4) {
  int i0 = blockIdx.x * 256 + threadIdx.x;
  int stride = gridDim.x * 256;
  for (int i = i0; i < n4; i += stride) {
    float4 v = *(const float4*)(z + 4 * (long long)i);
    f16x4 c;
    c[0] = (f16)v.x; c[1] = (f16)v.y; c[2] = (f16)v.z; c[3] = (f16)v.w;
    *(f16x4*)(z16 + 4 * (long long)i) = c;
    int node = i >> 5, sl = i & 31;
    *(f16x4*)(Xc + (long long)node * 256 + 128 + 4 * sl) = c;
  }
  for (int i = i0; i < E; i += stride) atomicAdd(&degi[dst[i]], 1);
  for (int i = i0; i < 425984; i += stride) {
    if (i < 32768) {
      int n = i >> 8, k = i & 255;
      wgs[i] = (f16)((k < 128) ? Wg[k * 128 + n] : Ws[(k - 128) * 128 + n]);
    } else if (i < 98304) {
      int j = i - 32768, c = j >> 7, k = j & 127;
      wt1[j] = (f16)W1[k * 512 + c];
    } else if (i < 360448) {
      int j = i - 98304, c = j >> 9, k = j & 511;
      wt2[j] = (f16)W2[k * 512 + c];
    } else {
      int j = i - 360448, c = j >> 9, k = j & 511;
      wt3[j] = (f16)W3[k * 128 + c];
    }
  }
}

// ---- gather + mean -> Xc mean-half: 16 lanes/node, f16x8 loads ----
__global__ __launch_bounds__(256) void gather_xcat(
    const f16* __restrict__ z16, const int* __restrict__ row_start,
    const int* __restrict__ adj, f16* __restrict__ Xc, int N) {
  int node = (blockIdx.x * 256 + threadIdx.x) >> 4;
  if (node >= N) return;
  int lane = threadIdx.x & 15;
  int beg = row_start[node], end = row_start[node + 1];
  float a0 = 0, a1 = 0, a2 = 0, a3 = 0, a4 = 0, a5 = 0, a6 = 0, a7 = 0;
#pragma unroll
  for (int j = 0; j < 8; ++j) {
    int idx = beg + j;
    bool vld = idx < end;
    int nb = adj[vld ? idx : beg];
    f16x8 x = *(const f16x8*)(z16 + (long long)nb * 128 + 8 * lane);
    float w = vld ? 1.0f : 0.0f;
    a0 += w * (float)x[0]; a1 += w * (float)x[1];
    a2 += w * (float)x[2]; a3 += w * (float)x[3];
    a4 += w * (float)x[4]; a5 += w * (float)x[5];
    a6 += w * (float)x[6]; a7 += w * (float)x[7];
  }
  int i = beg + 8;
  if (i < end) {
    float b0 = 0, b1 = 0, b2 = 0, b3 = 0, b4 = 0, b5 = 0, b6 = 0, b7 = 0;
    for (; i + 2 <= end; i += 2) {
      int n0 = adj[i], n1 = adj[i + 1];
      f16x8 v0 = *(const f16x8*)(z16 + (long long)n0 * 128 + 8 * lane);
      f16x8 v1 = *(const f16x8*)(z16 + (long long)n1 * 128 + 8 * lane);
      a0 += (float)v0[0]; a1 += (float)v0[1]; a2 += (float)v0[2]; a3 += (float)v0[3];
      a4 += (float)v0[4]; a5 += (float)v0[5]; a6 += (float)v0[6]; a7 += (float)v0[7];
      b0 += (float)v1[0]; b1 += (float)v1[1]; b2 += (float)v1[2]; b3 += (float)v1[3];
      b4 += (float)v1[4]; b5 += (float)v1[5]; b6 += (float)v1[6]; b7 += (float)v1[7];
    }
    for (; i < end; ++i) {
      f16x8 v = *(const f16x8*)(z16 + (long long)adj[i] * 128 + 8 * lane);
      a0 += (float)v[0]; a1 += (float)v[1]; a2 += (float)v[2]; a3 += (float)v[3];
      a4 += (float)v[4]; a5 += (float)v[5]; a6 += (float)v[6]; a7 += (float)v[7];
    }
    a0 += b0; a1 += b1; a2 += b2; a3 += b3;
    a4 += b4; a5 += b5; a6 += b6; a7 += b7;
  }
  int dg = end - beg;
  float inv = 1.0f / (float)(dg > 1 ? dg : 1);
  long long o = (long long)node * 256;
  f16x8 m;
  m[0] = (f16)(a0 * inv); m[1] = (f16)(a1 * inv);
  m[2] = (f16)(a2 * inv); m[3] = (f16)(a3 * inv);
  m[4] = (f16)(a4 * inv); m[5] = (f16)(a5 * inv);
  m[6] = (f16)(a6 * inv); m[7] = (f16)(a7 * inv);
  *(f16x8*)(Xc + o + 8 * lane) = m;
}

// ======================= fused L1+L2 (exact R17 proven version) =======================
__global__ __launch_bounds__(256) void fused12(
    const f16* __restrict__ Xc, const f16* __restrict__ wgs,
    const f16* __restrict__ wt1, const float* __restrict__ bg,
    const float* __restrict__ b1, f16* __restrict__ h2) {
  __shared__ __align__(16) char L[49152];
  const int tid = threadIdx.x;
  const int wid = tid >> 6, lane = tid & 63;
  const int wm = wid & 1, wn = wid >> 1;  // 2x2
  const int lr = lane & 15, lq = lane >> 4;
  const int key = lr & 7;
  const long long m0 = (long long)blockIdx.x * 128;
  const f16* Ag = Xc + m0 * 256;

  f32x4 acc[4][4];
#pragma unroll
  for (int i = 0; i < 4; ++i)
#pragma unroll
    for (int j = 0; j < 4; ++j)
#pragma unroll
      for (int r = 0; r < 4; ++r) acc[i][j][r] = 0.0f;

#pragma unroll 1
  for (int k0 = 0; k0 < 256; k0 += 64) {
#pragma unroll
    for (int c = 0; c < 4; ++c) {
      int f = c * 256 + tid;
      int row = f >> 3, ss = (f & 7) ^ (row & 7);
      async_load16(Ag + (long long)row * 256 + k0 + ss * 8, L + f * 16);
    }
#pragma unroll
    for (int c = 0; c < 4; ++c) {
      int f = c * 256 + tid;
      int row = f >> 3, ss = (f & 7) ^ (row & 7);
      async_load16(wgs + row * 256 + k0 + ss * 8, L + 16384 + f * 16);
    }
    __syncthreads();
#pragma unroll
    for (int kk = 0; kk < 64; kk += 32) {
      const int co = (((kk >> 3) + lq) ^ key) * 16;
      f16x8 a[4], b[4];
#pragma unroll
      for (int i = 0; i < 4; ++i)
        a[i] = *reinterpret_cast<const f16x8*>(L + (wm * 64 + i * 16 + lr) * 128 + co);
#pragma unroll
      for (int j = 0; j < 4; ++j)
        b[j] = *reinterpret_cast<const f16x8*>(L + 16384 + (wn * 64 + j * 16 + lr) * 128 + co);
#pragma unroll
      for (int i = 0; i < 4; ++i)
#pragma unroll
        for (int j = 0; j < 4; ++j)
          acc[i][j] = __builtin_amdgcn_mfma_f32_16x16x32_f16(a[i], b[j], acc[i][j], 0, 0, 0);
    }
    __syncthreads();
  }

#pragma unroll
  for (int i = 0; i < 4; ++i)
#pragma unroll
    for (int j = 0; j < 4; ++j) {
      int col = wn * 64 + j * 16 + lr;
      float bv = bg[col];
#pragma unroll
      for (int r = 0; r < 4; ++r) {
        int row = wm * 64 + i * 16 + lq * 4 + r;
        float v = fmaxf(acc[i][j][r] + bv, 0.0f);
        *reinterpret_cast<f16*>(L + row * 256 + (((col >> 3) ^ (row & 7)) * 16) +
                                (col & 7) * 2) = (f16)v;
      }
    }
  __syncthreads();

#pragma unroll 1
  for (int cb = 0; cb < 4; ++cb) {
#pragma unroll
    for (int i = 0; i < 4; ++i)
#pragma unroll
      for (int j = 0; j < 4; ++j)
#pragma unroll
        for (int r = 0; r < 4; ++r) acc[i][j][r] = 0.0f;

#pragma unroll 1
    for (int kc = 0; kc < 2; ++kc) {
#pragma unroll
      for (int c = 0; c < 4; ++c) {
        int f = c * 256 + tid;
        int row = f >> 3, ss = (f & 7) ^ (row & 7);
        async_load16(wt1 + (long long)(cb * 128 + row) * 128 + kc * 64 + ss * 8,
                     L + 32768 + f * 16);
      }
      __syncthreads();
#pragma unroll
      for (int kk = 0; kk < 64; kk += 32) {
        const int aslot = kc * 8 + (kk >> 3) + lq;
        const int bco = (((kk >> 3) + lq) ^ key) * 16;
        f16x8 a[4], b[4];
#pragma unroll
        for (int i = 0; i < 4; ++i)
          a[i] = *reinterpret_cast<const f16x8*>(
              L + (wm * 64 + i * 16 + lr) * 256 + (aslot ^ key) * 16);
#pragma unroll
        for (int j = 0; j < 4; ++j)
          b[j] = *reinterpret_cast<const f16x8*>(
              L + 32768 + (wn * 64 + j * 16 + lr) * 128 + bco);
#pragma unroll
        for (int i = 0; i < 4; ++i)
#pragma unroll
          for (int j = 0; j < 4; ++j)
            acc[i][j] = __builtin_amdgcn_mfma_f32_16x16x32_f16(a[i], b[j], acc[i][j], 0, 0, 0);
      }
      __syncthreads();
    }
#pragma unroll
    for (int i = 0; i < 4; ++i)
#pragma unroll
      for (int j = 0; j < 4; ++j) {
        int colg = cb * 128 + wn * 64 + j * 16 + lr;
        float bv = b1[colg];
#pragma unroll
        for (int r = 0; r < 4; ++r) {
          long long row = m0 + wm * 64 + i * 16 + lq * 4 + r;
          h2[row * 512 + colg] = (f16)fast_tanh(acc[i][j][r] + bv);
        }
      }
  }
}

// --------- R5/R11 proven drain GEMM (BK=64, single buffer, swizzled) ----------
// SWZ=1: 1D grid, (bx,0),(bx,1) adjacent -> A-panel reuse (R19/R20 variant).
template <int K, int NOUT, int WM, int WN, int MI, int ACT, bool OUTF32, int SWZ>
__global__ __launch_bounds__(WM * WN * 64) void gemm_r(
    const f16* __restrict__ X, const f16* __restrict__ Wt,
    const float* __restrict__ bias, void* __restrict__ OutV, int M) {
  constexpr int NJ = 4;
  constexpr int BM = WM * MI * 16;
  constexpr int BN = WN * NJ * 16;
  constexpr int NTHR = WM * WN * 64;
  constexpr int CA = (BM * 128) / (NTHR * 16);
  constexpr int CB = (BN * 128) / (NTHR * 16);
  __shared__ __align__(16) f16 As[BM * 64];
  __shared__ __align__(16) f16 Bs[BN * 64];

  const int tid = threadIdx.x;
  const int wid = tid >> 6, lane = tid & 63;
  const int wm = wid / WN, wn = wid % WN;
  const int lr = lane & 15, lq = lane >> 4;
  const int rxor = lr & 7;

  int bx, by;
  if constexpr (SWZ) {
    int bid = blockIdx.x;
    int wid2 = bid;
    if ((gridDim.x & 7) == 0) {
      int q = gridDim.x >> 3;
      wid2 = (bid & 7) * q + (bid >> 3);
    }
    bx = wid2 >> 1;
    by = wid2 & 1;
  } else {
    bx = blockIdx.x; by = blockIdx.y;
  }
  const long long m0 = (long long)bx * BM;
  const int n0 = by * BN;

  const f16* Ag = X + m0 * K;
  const f16* Bg = Wt + (long long)n0 * K;

  long long aOff[CA], bOff[CB];
#pragma unroll
  for (int c = 0; c < CA; ++c) {
    int f = c * NTHR + tid;
    int row = f >> 3, ss = (f & 7) ^ (row & 7);
    aOff[c] = (long long)row * K + ss * 8;
  }
#pragma unroll
  for (int c = 0; c < CB; ++c) {
    int f = c * NTHR + tid;
    int row = f >> 3, ss = (f & 7) ^ (row & 7);
    bOff[c] = (long long)row * K + ss * 8;
  }

  f32x4 acc[MI][NJ];
#pragma unroll
  for (int i = 0; i < MI; ++i)
#pragma unroll
    for (int j = 0; j < NJ; ++j)
#pragma unroll
      for (int r = 0; r < 4; ++r) acc[i][j][r] = 0.0f;

#pragma unroll 1
  for (int k0 = 0; k0 < K; k0 += 64) {
#pragma unroll
    for (int c = 0; c < CA; ++c)
      async_load16(Ag + aOff[c] + k0, (char*)As + c * NTHR * 16 + wid * 1024);
#pragma unroll
    for (int c = 0; c < CB; ++c)
      async_load16(Bg + bOff[c] + k0, (char*)Bs + c * NTHR * 16 + wid * 1024);
    __syncthreads();
#pragma unroll
    for (int kk = 0; kk < 64; kk += 32) {
      const int co = (((kk >> 3) + lq) ^ rxor) * 16;
      f16x8 a[MI], b[NJ];
#pragma unroll
      for (int i = 0; i < MI; ++i)
        a[i] = *reinterpret_cast<const f16x8*>(
            (const char*)As + (wm * MI * 16 + i * 16 + lr) * 128 + co);
#pragma unroll
      for (int j = 0; j < NJ; ++j)
        b[j] = *reinterpret_cast<const f16x8*>(
            (const char*)Bs + (wn * NJ * 16 + j * 16 + lr) * 128 + co);
#pragma unroll
      for (int i = 0; i < MI; ++i)
#pragma unroll
        for (int j = 0; j < NJ; ++j)
          acc[i][j] = __builtin_amdgcn_mfma_f32_16x16x32_f16(a[i], b[j], acc[i][j], 0, 0, 0);
    }
    __syncthreads();
  }

#pragma unroll
  for (int i = 0; i < MI; ++i) {
#pragma unroll
    for (int j = 0; j < NJ; ++j) {
      int col = n0 + wn * NJ * 16 + j * 16 + lr;
      float bv = bias[col];
#pragma unroll
      for (int r = 0; r < 4; ++r) {
        long long row = m0 + wm * MI * 16 + i * 16 + lq * 4 + r;
        if (row < M) {
          float v = acc[i][j][r] + bv;
          if (ACT == 1) v = fmaxf(v, 0.0f);
          else if (ACT == 2) v = fast_tanh(v);
          if constexpr (OUTF32)
            ((float*)OutV)[row * NOUT + col] = v;
          else
            ((f16*)OutV)[row * NOUT + col] = (f16)v;
        }
      }
    }
  }
}

extern "C" void kernel_launch(void* const* d_in, const int* in_sizes, int n_in,
                              void* d_out, int out_size, void* d_ws, size_t ws_size,
                              hipStream_t stream) {
  const float* z  = (const float*)d_in[0];
  const int*   ei = (const int*)d_in[1];
  const float* Wg = (const float*)d_in[2];
  const float* Ws = (const float*)d_in[3];
  const float* bg = (const float*)d_in[4];
  const float* W1 = (const float*)d_in[5];
  const float* b1 = (const float*)d_in[6];
  const float* W2 = (const float*)d_in[7];
  const float* b2 = (const float*)d_in[8];
  const float* W3 = (const float*)d_in[9];
  const float* b3 = (const float*)d_in[10];

  const int Nn = in_sizes[0] / 128;
  const int E  = in_sizes[1] / 2;
  const int* src = ei;
  const int* dst = ei + E;
  const int nb = (Nn + 1023) / 1024;
  const int gm256 = (Nn + 255) / 256;
  const long long Mpad = (long long)gm256 * 256;
  const int gm128 = gm256 * 2;

  // workspace overlay (peak ~207 MB), R17/R20 layout:
  //   [0, 51.2M)        Xc    (prep/gather -> fused12)
  //   [51.2, ~81M)      CSR + z16 (dead after gather)
  //   [0, 102.4M)       h3    (gemm3 -> gemm4; overlays Xc+CSR+z16)
  //   [102.4, 204.8M)   h2    (fused12 -> gemm3)
  //   [204.8M, ...)     prepped weights (~1.7 MB)
  char* base = (char*)d_ws;
  const size_t XCB = (size_t)Mpad * 256 * 2;
  const size_t H3B = (size_t)Mpad * 512 * 2;
  f16* Xc = (f16*)(base);
  f16* h3 = (f16*)(base);
  size_t off = XCB;
  auto alloc = [&](size_t b) -> void* {
    void* p = base + off;
    off += (b + 255) & ~(size_t)255;
    return p;
  };
  int* degi      = (int*)alloc((size_t)Nn * 4);
  int* row_start = (int*)alloc((size_t)(Nn + 1) * 4);
  int* cursor    = (int*)alloc((size_t)Nn * 4);
  int* adj       = (int*)alloc((size_t)(E + 8) * 4);
  int* bsum      = (int*)alloc((size_t)nb * 4);
  f16* z16       = (f16*)alloc((size_t)Nn * 128 * 2);
  off = H3B;
  f16* h2  = (f16*)alloc((size_t)Mpad * 512 * 2);
  f16* wgs = (f16*)alloc((size_t)128 * 256 * 2);
  f16* wt1 = (f16*)alloc((size_t)512 * 128 * 2);
  f16* wt2 = (f16*)alloc((size_t)512 * 512 * 2);
  f16* wt3 = (f16*)alloc((size_t)128 * 512 * 2);

  // CSR + prep
  hipMemsetAsync(degi, 0, (size_t)Nn * 4, stream);
  fused_prep<<<2048, 256, 0, stream>>>(dst, degi, E, Wg, Ws, W1, W2, W3,
                                       wgs, wt1, wt2, wt3, z, z16, Xc, Nn * 32);
  scan_partial<<<nb, 256, 0, stream>>>(degi, bsum, Nn);
  scan_final<<<nb, 256, 0, stream>>>(degi, bsum, row_start, cursor, nb, Nn, E);
  fill_adj<<<(E + 255) / 256, 256, 0, stream>>>(src, dst, cursor, adj, E);

  // gather mean-half (16 lanes/node, f16x8)
  {
    long long tot = (long long)Nn * 16;
    gather_xcat<<<(int)((tot + 255) / 256), 256, 0, stream>>>(z16, row_start, adj, Xc, Nn);
  }

  // MLP: fused L1+L2 (R17); gemm3 1D paired launch (R20); gemm4 (R17/R20).
  fused12<<<gm128, 256, 0, stream>>>(Xc, wgs, wt1, bg, b1, h2);
  gemm_r<512, 512, 2, 4, 4, 2, false, 1><<<gm128 * 2, 512, 0, stream>>>(h2, wt2, b2, (void*)h3, Nn);
  gemm_r<512, 128, 4, 2, 4, 0, true, 0><<<dim3(gm256, 1), 512, 0, stream>>>(h3, wt3, b3, d_out, Nn);
}